// Round 26
// baseline (75.956 us; speedup 1.0000x reference)
//
#include <hip/hip_runtime.h>
#include <math.h>

#define NE 8
#define NT 512
#define NH 1024
#define NF 2816
#define TWO_F (2*NF)      // 5632
#define HP (NH/8)         // 128 packed rows for w13
#define FP (NF/8)         // 352 packed rows for w2
#define H_GROUPS 8
#define F_GROUPS 22

typedef __attribute__((ext_vector_type(4))) int   int4v;
typedef __attribute__((ext_vector_type(4))) float f32x4;
typedef __attribute__((ext_vector_type(8))) short short8;

__device__ inline short f2bf(float f) {
    unsigned u = __float_as_uint(f);
    u += 0x7FFFu + ((u >> 16) & 1u);   // RNE
    return (short)(u >> 16);
}
__device__ inline float bf2f(short s) {
    return __uint_as_float(((unsigned)(unsigned short)s) << 16);
}

// async global->LDS DMA, 16 B per lane; lds base must be wave-uniform
__device__ inline void load_lds_16(const void* gsrc, void* ldst) {
    __builtin_amdgcn_global_load_lds(
        (const __attribute__((address_space(1))) unsigned*)gsrc,
        (__attribute__((address_space(3))) unsigned*)ldst, 16, 0, 0);
}

// 16 nibbles (rows kp, kp+1 packed ints) -> 16 int8 bytes = (nib - 8)
__device__ inline int4v unpack16(int q0, int q1) {
    int e0 = q0 & 0x0F0F0F0F, o0 = ((unsigned)q0 >> 4) & 0x0F0F0F0F;
    int e1 = q1 & 0x0F0F0F0F, o1 = ((unsigned)q1 >> 4) & 0x0F0F0F0F;
    int4v b;
    b[0] = (__builtin_amdgcn_perm(o0, e0, 0x05010400) + 0x78787878) ^ 0x80808080;
    b[1] = (__builtin_amdgcn_perm(o0, e0, 0x07030602) + 0x78787878) ^ 0x80808080;
    b[2] = (__builtin_amdgcn_perm(o1, e1, 0x05010400) + 0x78787878) ^ 0x80808080;
    b[3] = (__builtin_amdgcn_perm(o1, e1, 0x07030602) + 0x78787878) ^ 0x80808080;
    return b;
}

// unpack 8 int4 nibbles (one packed int, k-order) -> (nib-8)*sc as bf16
__device__ inline short8 unpack_scale_bf16(int q, float sc) {
    float v[8];
#pragma unroll
    for (int j = 0; j < 8; ++j) {
        unsigned u = 0x4B000000u | (((unsigned)q >> (4 * j)) & 15u);
        v[j] = __uint_as_float(u) - 8388616.0f;   // exact (nib - 8)
    }
    union { short8 s; unsigned u[4]; } r;
#pragma unroll
    for (int j = 0; j < 4; ++j) {
        unsigned lo = __float_as_uint(v[2 * j] * sc);
        unsigned hi = __float_as_uint(v[2 * j + 1] * sc);
        r.u[j] = __builtin_amdgcn_perm(hi, lo, 0x07060302u);  // [bf16(lo), bf16(hi)]
    }
    return r.s;
}

__device__ inline int pack4(const int* b) {
    return (b[0] & 255) | ((b[1] & 255) << 8) | ((b[2] & 255) << 16) | ((b[3] & 255) << 24);
}

// ---- routing (softmax->top2->renorm) + stable binning + prefix + maps ------
__global__ __launch_bounds__(512) void route_bin_kernel(
        const float* __restrict__ logits,
        float* __restrict__ topk_w,
        int* __restrict__ counts,
        int* __restrict__ offs,
        int* __restrict__ tok_list,
        int* __restrict__ rowmap,
        int* __restrict__ inv) {
    __shared__ int sh_e[2 * NT];
    __shared__ int sh_cnt[NE], sh_off[NE];
    const int t = threadIdx.x;   // one token per thread, NT==512
    float l[NE];
#pragma unroll
    for (int e = 0; e < NE; ++e) l[e] = logits[t * NE + e];
    int i0 = 0; float v0 = l[0];
#pragma unroll
    for (int e = 1; e < NE; ++e) { if (l[e] > v0) { v0 = l[e]; i0 = e; } }
    int i1 = -1; float v1 = -INFINITY;
#pragma unroll
    for (int e = 0; e < NE; ++e) {
        if (e == i0) continue;
        if (l[e] > v1) { v1 = l[e]; i1 = e; }
    }
    float e1 = expf(v1 - v0);
    float invp = 1.0f / (1.0f + e1);
    topk_w[t * 2 + 0] = invp;
    topk_w[t * 2 + 1] = e1 * invp;
    sh_e[t * 2 + 0] = i0;
    sh_e[t * 2 + 1] = i1;
    __syncthreads();
    const int w = t >> 6, lane = t & 63;
    int base = 0;
    for (int chunk = 0; chunk < 16; ++chunk) {
        int j = chunk * 64 + lane;
        bool m = (sh_e[j] == w);
        unsigned long long mask = __ballot(m);
        if (m) {
            int pos = base + __popcll(mask & ((1ull << lane) - 1ull));
            tok_list[w * NT + pos] = j;   // j = t*2 + slot
        }
        base += __popcll(mask);
    }
    if (lane == 0) { counts[w] = base; sh_cnt[w] = base; }
    __syncthreads();
    if (t == 0) {
        int o = 0;
#pragma unroll
        for (int e = 0; e < NE; ++e) { sh_off[e] = o; offs[e] = o; o += sh_cnt[e]; }
    }
    __syncthreads();
    const int myoff = sh_off[w];
    for (int i = lane; i < sh_cnt[w]; i += 64) {
        const int j = tok_list[w * NT + i];
        rowmap[myoff + i] = j;      // sorted row -> t2s
        inv[j] = myoff + i;         // t2s -> sorted row
    }
}

// -------- gather + x -> int8 (per-row scale), sorted ------
__global__ __launch_bounds__(256) void quant_x_kernel(const float* __restrict__ x,
                                                      const int* __restrict__ rowmap,
                                                      char* __restrict__ xq,
                                                      float* __restrict__ sx) {
    __shared__ float wmax[4];
    const int r = blockIdx.x;              // sorted row
    const int t = rowmap[r] >> 1;
    const int tid = threadIdx.x;
    f32x4 v = *(const f32x4*)(x + (size_t)t * NH + tid * 4);
    float m = fmaxf(fmaxf(fabsf(v[0]), fabsf(v[1])), fmaxf(fabsf(v[2]), fabsf(v[3])));
#pragma unroll
    for (int off = 32; off >= 1; off >>= 1)
        m = fmaxf(m, __shfl_xor(m, off, 64));
    if ((tid & 63) == 0) wmax[tid >> 6] = m;
    __syncthreads();
    float amax = fmaxf(fmaxf(wmax[0], wmax[1]), fmaxf(wmax[2], wmax[3]));
    float scale = (amax > 0.f) ? amax / 127.f : 0.f;
    float invs  = (amax > 0.f) ? 127.f / amax : 0.f;
    if (tid == 0) sx[r] = scale;
    int bq[4];
#pragma unroll
    for (int j = 0; j < 4; ++j) {
        float qh = rintf(v[j] * invs);
        qh = fminf(fmaxf(qh, -127.f), 127.f);
        bq[j] = (int)qh;
    }
    ((int*)xq)[r * (NH / 4) + tid] = pack4(bq);
}

// ------- GEMM1 + silu fused (single int8, async DMA dbuf, 64M tile) --------
// block 64M x 32F(g)+32F(u); 4 waves M-split (16 rows each); rolled kb loop.
__global__ __launch_bounds__(256) void gemm1_act_kernel(
        const char*  __restrict__ xq,
        const float* __restrict__ sx,
        const int*   __restrict__ w13q,
        const float* __restrict__ s13,
        const int*   __restrict__ counts,
        const int*   __restrict__ offs,
        short* __restrict__ a_s) {
    __shared__ int lds[2][2][16][32];      // [buf][gu][row][col] — linear (DMA)
    const int e = blockIdx.z;
    const int me = counts[e];
    const int mtile = blockIdx.y;
    if (mtile * 64 >= me) return;
    const int base = offs[e];
    const int tid = threadIdx.x;
    const int w = tid >> 6, l = tid & 63;
    const int lr = l & 15, kg = l >> 4;
    const int rb = mtile * 64 + w * 16;
    const int cF0 = blockIdx.x * 32;

    // staging source for this lane (wave w quarter): gu=w>>1, row=(w&1)*8+(l>>3)
    const int sgu  = w >> 1;
    const int srow = (w & 1) * 8 + (l >> 3);
    const int scol = (l & 7) * 4;
    const int* gW = w13q + (size_t)e * HP * TWO_F + (size_t)srow * TWO_F
                  + cF0 + sgu * NF + scol;

    int i = rb + lr; if (i >= me) i = me - 1;
    const char* pA = xq + (size_t)(base + i) * NH;
    const float* sb = s13 + (size_t)e * H_GROUPS * TWO_F + cF0 + lr;

    f32x4 facc[2][2];   // [gu][ns]
#pragma unroll
    for (int gu = 0; gu < 2; ++gu)
#pragma unroll
        for (int ns = 0; ns < 2; ++ns) facc[gu][ns] = (f32x4)0.f;

    // prologue: DMA kb=0 into buf 0 (wave-uniform LDS base + lane*16)
    load_lds_16(gW, &lds[0][sgu][(w & 1) * 8][0]);
    __syncthreads();
    int buf = 0;
#pragma unroll 1
    for (int kb = 0; kb < H_GROUPS; ++kb) {
        if (kb < H_GROUPS - 1)   // async DMA next tile; completes by next barrier
            load_lds_16(gW + (size_t)(kb + 1) * 16 * TWO_F,
                        &lds[buf ^ 1][sgu][(w & 1) * 8][0]);
        float scl[2][2];
        scl[0][0] = sb[(size_t)kb * TWO_F];
        scl[0][1] = sb[(size_t)kb * TWO_F + 16];
        scl[1][0] = sb[(size_t)kb * TWO_F + NF];
        scl[1][1] = sb[(size_t)kb * TWO_F + NF + 16];
        int4v ah[2];   // [ks]
#pragma unroll
        for (int ks = 0; ks < 2; ++ks) {
            const int k0 = kb * 128 + ks * 64 + kg * 16;
            ah[ks] = *(const int4v*)(pA + k0);
        }
#pragma unroll
        for (int gu = 0; gu < 2; ++gu)
#pragma unroll
            for (int ns = 0; ns < 2; ++ns) {
                int4v ihh = (int4v)0;
#pragma unroll
                for (int ks = 0; ks < 2; ++ks) {
                    const int row = ks * 8 + kg * 2;
                    const int c = ns * 16 + lr;
                    const int4v b = unpack16(lds[buf][gu][row][c],
                                             lds[buf][gu][row + 1][c]);
                    ihh = __builtin_amdgcn_mfma_i32_16x16x64_i8(ah[ks], b, ihh, 0, 0, 0);
                }
                const float c2 = scl[gu][ns];
#pragma unroll
                for (int r = 0; r < 4; ++r)
                    facc[gu][ns][r] += c2 * (float)ihh[r];
            }
        __syncthreads();   // drains DMA (vmcnt) + protects buf swap
        buf ^= 1;
    }
    // epilogue: C row = kg*4 + r; cols cF0 + ns*16 + lr
#pragma unroll
    for (int r = 0; r < 4; ++r) {
        const int orow = rb + kg * 4 + r;
        if (orow < me) {
            const int rg = base + orow;
            const float sxm = sx[rg];
#pragma unroll
            for (int ns = 0; ns < 2; ++ns) {
                const float g = sxm * facc[0][ns][r];
                const float u = sxm * facc[1][ns][r];
                const float aval = (g / (1.0f + __expf(-g))) * u;
                a_s[(size_t)rg * NF + cF0 + ns * 16 + lr] = f2bf(aval);
            }
        }
    }
}

// ------- GEMM2 (bf16 MFMA, sorted A): 16M x 32N, K-split(4) + LDS reduce ---
// Writes raw y to sorted y_s (plain stores, no atomics, no pre-zero needed).
__global__ __launch_bounds__(256) void gemm2_kernel(
        const short* __restrict__ a_s,
        const int*   __restrict__ w2q,
        const float* __restrict__ s2,
        const int*   __restrict__ counts,
        const int*   __restrict__ offs,
        float* __restrict__ y_s) {
    __shared__ float red[3][16][33];
    const int e = blockIdx.z;
    const int me = counts[e];
    const int mtile = blockIdx.y;
    if (mtile * 16 >= me) return;
    const int base = offs[e];
    const int tid = threadIdx.x;
    const int kh = tid >> 6, l = tid & 63;
    const int lr = l & 15, kg = l >> 4;
    const int rb = mtile * 16;
    const int cb = blockIdx.x * 32;

    int i = rb + lr; if (i >= me) i = me - 1;
    const short* aA = a_s + (size_t)(base + i) * NF;

    f32x4 facc[2];
#pragma unroll
    for (int ns = 0; ns < 2; ++ns) facc[ns] = (f32x4)0.f;

#pragma unroll 1
    for (int g = kh; g < F_GROUPS; g += 4) {
        float sc[2];
#pragma unroll
        for (int ns = 0; ns < 2; ++ns)
            sc[ns] = s2[(size_t)(e * F_GROUPS + g) * NH + cb + ns * 16 + lr];
#pragma unroll
        for (int ks = 0; ks < 4; ++ks) {
            const int k0 = g * 128 + ks * 32;
            const short8 a = *(const short8*)(aA + k0 + kg * 8);
            const int kp = (k0 >> 3) + kg;
            const int* bq = w2q + ((size_t)e * FP + kp) * NH + cb + lr;
            int q[2];
#pragma unroll
            for (int ns = 0; ns < 2; ++ns) q[ns] = bq[ns * 16];
#pragma unroll
            for (int ns = 0; ns < 2; ++ns) {
                const short8 b = unpack_scale_bf16(q[ns], sc[ns]);
                facc[ns] = __builtin_amdgcn_mfma_f32_16x16x32_bf16(a, b, facc[ns], 0, 0, 0);
            }
        }
    }

    if (kh > 0) {
#pragma unroll
        for (int ns = 0; ns < 2; ++ns)
#pragma unroll
            for (int r = 0; r < 4; ++r)
                red[kh - 1][kg * 4 + r][ns * 16 + lr] = facc[ns][r];
    }
    __syncthreads();
    if (kh == 0) {
#pragma unroll
        for (int r = 0; r < 4; ++r) {
            const int rowLoc = kg * 4 + r;
            const int orow = rb + rowLoc;
            if (orow < me) {
                const int rg = base + orow;
#pragma unroll
                for (int ns = 0; ns < 2; ++ns) {
                    float v = facc[ns][r]
                            + red[0][rowLoc][ns * 16 + lr]
                            + red[1][rowLoc][ns * 16 + lr]
                            + red[2][rowLoc][ns * 16 + lr];
                    y_s[(size_t)rg * NH + cb + ns * 16 + lr] = v;
                }
            }
        }
    }
}

// ------- combine: out[t] = w0*y_s[inv[2t]] + w1*y_s[inv[2t+1]] -------------
__global__ __launch_bounds__(256) void combine_kernel(
        const float* __restrict__ y_s,
        const int*   __restrict__ inv,
        const float* __restrict__ topk_w,
        float* __restrict__ out) {
    const int t = blockIdx.x;
    const int c = threadIdx.x * 4;
    const float w0 = topk_w[2 * t];
    const float w1 = topk_w[2 * t + 1];
    const int r0 = inv[2 * t];
    const int r1 = inv[2 * t + 1];
    f32x4 y0 = *(const f32x4*)(y_s + (size_t)r0 * NH + c);
    f32x4 y1 = *(const f32x4*)(y_s + (size_t)r1 * NH + c);
    f32x4 o;
#pragma unroll
    for (int j = 0; j < 4; ++j) o[j] = w0 * y0[j] + w1 * y1[j];
    *(f32x4*)(out + (size_t)t * NH + c) = o;
}

extern "C" void kernel_launch(void* const* d_in, const int* in_sizes, int n_in,
                              void* d_out, int out_size, void* d_ws, size_t ws_size,
                              hipStream_t stream) {
    const float* x      = (const float*)d_in[0];
    const float* logits = (const float*)d_in[1];
    const int*   w13q   = (const int*)d_in[2];
    const int*   w2q    = (const int*)d_in[3];
    const float* s13    = (const float*)d_in[4];
    const float* s2     = (const float*)d_in[5];

    char* ws = (char*)d_ws;
    size_t o = 0;
    int*   counts   = (int*)(ws + o);   o += 4096;
    int*   offs     = (int*)(ws + o);   o += 4096;
    float* topk_w   = (float*)(ws + o); o += 4096;
    int*   tok_list = (int*)(ws + o);   o += 16384;
    int*   rowmap   = (int*)(ws + o);   o += 4096;
    int*   inv      = (int*)(ws + o);   o += 4096;
    float* sx       = (float*)(ws + o); o += 4096;
    char*  xq       = ws + o;           o += (size_t)2 * NT * NH;          // 1 MB
    short* a_s      = (short*)(ws + o); o += (size_t)2 * NT * NF * 2;      // 5.77 MB
    float* y_s      = (float*)(ws + o); o += (size_t)2 * NT * NH * 4;      // 4 MB

    route_bin_kernel<<<1, 512, 0, stream>>>(logits, topk_w, counts, offs,
                                            tok_list, rowmap, inv);
    quant_x_kernel<<<2 * NT, 256, 0, stream>>>(x, rowmap, xq, sx);
    gemm1_act_kernel<<<dim3(NF / 32, 8, NE), 256, 0, stream>>>(
        xq, sx, w13q, s13, counts, offs, a_s);
    gemm2_kernel<<<dim3(NH / 32, 32, NE), 256, 0, stream>>>(
        a_s, w2q, s2, counts, offs, y_s);
    combine_kernel<<<NT, 256, 0, stream>>>(y_s, inv, topk_w, (float*)d_out);
}

// Round 27
// 75.638 us; speedup vs baseline: 1.0042x; 1.0042x over previous
//
#include <hip/hip_runtime.h>
#include <math.h>

#define NE 8
#define NT 512
#define NH 1024
#define NF 2816
#define TWO_F (2*NF)      // 5632
#define HP (NH/8)         // 128 packed rows for w13
#define FP (NF/8)         // 352 packed rows for w2
#define H_GROUPS 8
#define F_GROUPS 22

typedef __attribute__((ext_vector_type(4))) int   int4v;
typedef __attribute__((ext_vector_type(4))) float f32x4;
typedef __attribute__((ext_vector_type(8))) short short8;

__device__ inline short f2bf(float f) {
    unsigned u = __float_as_uint(f);
    u += 0x7FFFu + ((u >> 16) & 1u);   // RNE
    return (short)(u >> 16);
}
__device__ inline float bf2f(short s) {
    return __uint_as_float(((unsigned)(unsigned short)s) << 16);
}

// async global->LDS DMA, 16 B per lane; lds base must be wave-uniform
__device__ inline void load_lds_16(const void* gsrc, void* ldst) {
    __builtin_amdgcn_global_load_lds(
        (const __attribute__((address_space(1))) unsigned*)gsrc,
        (__attribute__((address_space(3))) unsigned*)ldst, 16, 0, 0);
}

// 16 nibbles (rows kp, kp+1 packed ints) -> 16 int8 bytes = (nib - 8)
__device__ inline int4v unpack16(int q0, int q1) {
    int e0 = q0 & 0x0F0F0F0F, o0 = ((unsigned)q0 >> 4) & 0x0F0F0F0F;
    int e1 = q1 & 0x0F0F0F0F, o1 = ((unsigned)q1 >> 4) & 0x0F0F0F0F;
    int4v b;
    b[0] = (__builtin_amdgcn_perm(o0, e0, 0x05010400) + 0x78787878) ^ 0x80808080;
    b[1] = (__builtin_amdgcn_perm(o0, e0, 0x07030602) + 0x78787878) ^ 0x80808080;
    b[2] = (__builtin_amdgcn_perm(o1, e1, 0x05010400) + 0x78787878) ^ 0x80808080;
    b[3] = (__builtin_amdgcn_perm(o1, e1, 0x07030602) + 0x78787878) ^ 0x80808080;
    return b;
}

// unpack 8 int4 nibbles (one packed int, k-order) -> (nib-8)*sc as bf16
__device__ inline short8 unpack_scale_bf16(int q, float sc) {
    float v[8];
#pragma unroll
    for (int j = 0; j < 8; ++j) {
        unsigned u = 0x4B000000u | (((unsigned)q >> (4 * j)) & 15u);
        v[j] = __uint_as_float(u) - 8388616.0f;   // exact (nib - 8)
    }
    union { short8 s; unsigned u[4]; } r;
#pragma unroll
    for (int j = 0; j < 4; ++j) {
        unsigned lo = __float_as_uint(v[2 * j] * sc);
        unsigned hi = __float_as_uint(v[2 * j + 1] * sc);
        r.u[j] = __builtin_amdgcn_perm(hi, lo, 0x07060302u);  // [bf16(lo), bf16(hi)]
    }
    return r.s;
}

__device__ inline int pack4(const int* b) {
    return (b[0] & 255) | ((b[1] & 255) << 8) | ((b[2] & 255) << 16) | ((b[3] & 255) << 24);
}

// ---- routing (softmax->top2->renorm) + stable binning + prefix + maps ------
__global__ __launch_bounds__(512) void route_bin_kernel(
        const float* __restrict__ logits,
        float* __restrict__ topk_w,
        int* __restrict__ counts,
        int* __restrict__ offs,
        int* __restrict__ tok_list,
        int* __restrict__ rowmap,
        int* __restrict__ inv) {
    __shared__ int sh_e[2 * NT];
    __shared__ int sh_cnt[NE], sh_off[NE];
    const int t = threadIdx.x;   // one token per thread, NT==512
    float l[NE];
#pragma unroll
    for (int e = 0; e < NE; ++e) l[e] = logits[t * NE + e];
    int i0 = 0; float v0 = l[0];
#pragma unroll
    for (int e = 1; e < NE; ++e) { if (l[e] > v0) { v0 = l[e]; i0 = e; } }
    int i1 = -1; float v1 = -INFINITY;
#pragma unroll
    for (int e = 0; e < NE; ++e) {
        if (e == i0) continue;
        if (l[e] > v1) { v1 = l[e]; i1 = e; }
    }
    float e1 = expf(v1 - v0);
    float invp = 1.0f / (1.0f + e1);
    topk_w[t * 2 + 0] = invp;
    topk_w[t * 2 + 1] = e1 * invp;
    sh_e[t * 2 + 0] = i0;
    sh_e[t * 2 + 1] = i1;
    __syncthreads();
    const int w = t >> 6, lane = t & 63;
    int base = 0;
    for (int chunk = 0; chunk < 16; ++chunk) {
        int j = chunk * 64 + lane;
        bool m = (sh_e[j] == w);
        unsigned long long mask = __ballot(m);
        if (m) {
            int pos = base + __popcll(mask & ((1ull << lane) - 1ull));
            tok_list[w * NT + pos] = j;   // j = t*2 + slot
        }
        base += __popcll(mask);
    }
    if (lane == 0) { counts[w] = base; sh_cnt[w] = base; }
    __syncthreads();
    if (t == 0) {
        int o = 0;
#pragma unroll
        for (int e = 0; e < NE; ++e) { sh_off[e] = o; offs[e] = o; o += sh_cnt[e]; }
    }
    __syncthreads();
    const int myoff = sh_off[w];
    for (int i = lane; i < sh_cnt[w]; i += 64) {
        const int j = tok_list[w * NT + i];
        rowmap[myoff + i] = j;      // sorted row -> t2s
        inv[j] = myoff + i;         // t2s -> sorted row
    }
}

// -------- gather + x -> int8 (per-row scale), sorted ------
__global__ __launch_bounds__(256) void quant_x_kernel(const float* __restrict__ x,
                                                      const int* __restrict__ rowmap,
                                                      char* __restrict__ xq,
                                                      float* __restrict__ sx) {
    __shared__ float wmax[4];
    const int r = blockIdx.x;              // sorted row
    const int t = rowmap[r] >> 1;
    const int tid = threadIdx.x;
    f32x4 v = *(const f32x4*)(x + (size_t)t * NH + tid * 4);
    float m = fmaxf(fmaxf(fabsf(v[0]), fabsf(v[1])), fmaxf(fabsf(v[2]), fabsf(v[3])));
#pragma unroll
    for (int off = 32; off >= 1; off >>= 1)
        m = fmaxf(m, __shfl_xor(m, off, 64));
    if ((tid & 63) == 0) wmax[tid >> 6] = m;
    __syncthreads();
    float amax = fmaxf(fmaxf(wmax[0], wmax[1]), fmaxf(wmax[2], wmax[3]));
    float scale = (amax > 0.f) ? amax / 127.f : 0.f;
    float invs  = (amax > 0.f) ? 127.f / amax : 0.f;
    if (tid == 0) sx[r] = scale;
    int bq[4];
#pragma unroll
    for (int j = 0; j < 4; ++j) {
        float qh = rintf(v[j] * invs);
        qh = fminf(fmaxf(qh, -127.f), 127.f);
        bq[j] = (int)qh;
    }
    ((int*)xq)[r * (NH / 4) + tid] = pack4(bq);
}

// ------- GEMM1 + silu fused (single int8, async DMA dbuf, 64M tile) --------
// block 64M x 32F(g)+32F(u); 4 waves M-split (16 rows each); rolled kb loop.
__global__ __launch_bounds__(256) void gemm1_act_kernel(
        const char*  __restrict__ xq,
        const float* __restrict__ sx,
        const int*   __restrict__ w13q,
        const float* __restrict__ s13,
        const int*   __restrict__ counts,
        const int*   __restrict__ offs,
        short* __restrict__ a_s) {
    __shared__ int lds[2][2][16][32];      // [buf][gu][row][col] — linear (DMA)
    const int e = blockIdx.z;
    const int me = counts[e];
    const int mtile = blockIdx.y;
    if (mtile * 64 >= me) return;
    const int base = offs[e];
    const int tid = threadIdx.x;
    const int w = tid >> 6, l = tid & 63;
    const int lr = l & 15, kg = l >> 4;
    const int rb = mtile * 64 + w * 16;
    const int cF0 = blockIdx.x * 32;

    // staging source for this lane (wave w quarter): gu=w>>1, row=(w&1)*8+(l>>3)
    const int sgu  = w >> 1;
    const int srow = (w & 1) * 8 + (l >> 3);
    const int scol = (l & 7) * 4;
    const int* gW = w13q + (size_t)e * HP * TWO_F + (size_t)srow * TWO_F
                  + cF0 + sgu * NF + scol;

    int i = rb + lr; if (i >= me) i = me - 1;
    const char* pA = xq + (size_t)(base + i) * NH;
    const float* sb = s13 + (size_t)e * H_GROUPS * TWO_F + cF0 + lr;

    f32x4 facc[2][2];   // [gu][ns]
#pragma unroll
    for (int gu = 0; gu < 2; ++gu)
#pragma unroll
        for (int ns = 0; ns < 2; ++ns) facc[gu][ns] = (f32x4)0.f;

    // prologue: DMA kb=0 into buf 0 (wave-uniform LDS base + lane*16)
    load_lds_16(gW, &lds[0][sgu][(w & 1) * 8][0]);
    __syncthreads();
    int buf = 0;
#pragma unroll 1
    for (int kb = 0; kb < H_GROUPS; ++kb) {
        if (kb < H_GROUPS - 1)   // async DMA next tile; completes by next barrier
            load_lds_16(gW + (size_t)(kb + 1) * 16 * TWO_F,
                        &lds[buf ^ 1][sgu][(w & 1) * 8][0]);
        float scl[2][2];
        scl[0][0] = sb[(size_t)kb * TWO_F];
        scl[0][1] = sb[(size_t)kb * TWO_F + 16];
        scl[1][0] = sb[(size_t)kb * TWO_F + NF];
        scl[1][1] = sb[(size_t)kb * TWO_F + NF + 16];
        int4v ah[2];   // [ks]
#pragma unroll
        for (int ks = 0; ks < 2; ++ks) {
            const int k0 = kb * 128 + ks * 64 + kg * 16;
            ah[ks] = *(const int4v*)(pA + k0);
        }
#pragma unroll
        for (int gu = 0; gu < 2; ++gu)
#pragma unroll
            for (int ns = 0; ns < 2; ++ns) {
                int4v ihh = (int4v)0;
#pragma unroll
                for (int ks = 0; ks < 2; ++ks) {
                    const int row = ks * 8 + kg * 2;
                    const int c = ns * 16 + lr;
                    const int4v b = unpack16(lds[buf][gu][row][c],
                                             lds[buf][gu][row + 1][c]);
                    ihh = __builtin_amdgcn_mfma_i32_16x16x64_i8(ah[ks], b, ihh, 0, 0, 0);
                }
                const float c2 = scl[gu][ns];
#pragma unroll
                for (int r = 0; r < 4; ++r)
                    facc[gu][ns][r] += c2 * (float)ihh[r];
            }
        __syncthreads();   // drains DMA (vmcnt) + protects buf swap
        buf ^= 1;
    }
    // epilogue: C row = kg*4 + r; cols cF0 + ns*16 + lr
#pragma unroll
    for (int r = 0; r < 4; ++r) {
        const int orow = rb + kg * 4 + r;
        if (orow < me) {
            const int rg = base + orow;
            const float sxm = sx[rg];
#pragma unroll
            for (int ns = 0; ns < 2; ++ns) {
                const float g = sxm * facc[0][ns][r];
                const float u = sxm * facc[1][ns][r];
                const float aval = (g / (1.0f + __expf(-g))) * u;
                a_s[(size_t)rg * NF + cF0 + ns * 16 + lr] = f2bf(aval);
            }
        }
    }
}

// ------- GEMM2 (bf16 MFMA, sorted A): 16M x 32N, K-split(4) + LDS reduce ---
// Writes raw y to sorted y_s (plain stores, no atomics, no pre-zero needed).
__global__ __launch_bounds__(256) void gemm2_kernel(
        const short* __restrict__ a_s,
        const int*   __restrict__ w2q,
        const float* __restrict__ s2,
        const int*   __restrict__ counts,
        const int*   __restrict__ offs,
        float* __restrict__ y_s) {
    __shared__ float red[3][16][33];
    const int e = blockIdx.z;
    const int me = counts[e];
    const int mtile = blockIdx.y;
    if (mtile * 16 >= me) return;
    const int base = offs[e];
    const int tid = threadIdx.x;
    const int kh = tid >> 6, l = tid & 63;
    const int lr = l & 15, kg = l >> 4;
    const int rb = mtile * 16;
    const int cb = blockIdx.x * 32;

    int i = rb + lr; if (i >= me) i = me - 1;
    const short* aA = a_s + (size_t)(base + i) * NF;

    f32x4 facc[2];
#pragma unroll
    for (int ns = 0; ns < 2; ++ns) facc[ns] = (f32x4)0.f;

    for (int g = kh; g < F_GROUPS; g += 4) {
        float sc[2];
#pragma unroll
        for (int ns = 0; ns < 2; ++ns)
            sc[ns] = s2[(size_t)(e * F_GROUPS + g) * NH + cb + ns * 16 + lr];
#pragma unroll
        for (int ks = 0; ks < 4; ++ks) {
            const int k0 = g * 128 + ks * 32;
            const short8 a = *(const short8*)(aA + k0 + kg * 8);
            const int kp = (k0 >> 3) + kg;
            const int* bq = w2q + ((size_t)e * FP + kp) * NH + cb + lr;
            int q[2];
#pragma unroll
            for (int ns = 0; ns < 2; ++ns) q[ns] = bq[ns * 16];
#pragma unroll
            for (int ns = 0; ns < 2; ++ns) {
                const short8 b = unpack_scale_bf16(q[ns], sc[ns]);
                facc[ns] = __builtin_amdgcn_mfma_f32_16x16x32_bf16(a, b, facc[ns], 0, 0, 0);
            }
        }
    }

    if (kh > 0) {
#pragma unroll
        for (int ns = 0; ns < 2; ++ns)
#pragma unroll
            for (int r = 0; r < 4; ++r)
                red[kh - 1][kg * 4 + r][ns * 16 + lr] = facc[ns][r];
    }
    __syncthreads();
    if (kh == 0) {
#pragma unroll
        for (int r = 0; r < 4; ++r) {
            const int rowLoc = kg * 4 + r;
            const int orow = rb + rowLoc;
            if (orow < me) {
                const int rg = base + orow;
#pragma unroll
                for (int ns = 0; ns < 2; ++ns) {
                    float v = facc[ns][r]
                            + red[0][rowLoc][ns * 16 + lr]
                            + red[1][rowLoc][ns * 16 + lr]
                            + red[2][rowLoc][ns * 16 + lr];
                    y_s[(size_t)rg * NH + cb + ns * 16 + lr] = v;
                }
            }
        }
    }
}

// ------- combine: out[t] = w0*y_s[inv[2t]] + w1*y_s[inv[2t+1]] -------------
__global__ __launch_bounds__(256) void combine_kernel(
        const float* __restrict__ y_s,
        const int*   __restrict__ inv,
        const float* __restrict__ topk_w,
        float* __restrict__ out) {
    const int t = blockIdx.x;
    const int c = threadIdx.x * 4;
    const float w0 = topk_w[2 * t];
    const float w1 = topk_w[2 * t + 1];
    const int r0 = inv[2 * t];
    const int r1 = inv[2 * t + 1];
    f32x4 y0 = *(const f32x4*)(y_s + (size_t)r0 * NH + c);
    f32x4 y1 = *(const f32x4*)(y_s + (size_t)r1 * NH + c);
    f32x4 o;
#pragma unroll
    for (int j = 0; j < 4; ++j) o[j] = w0 * y0[j] + w1 * y1[j];
    *(f32x4*)(out + (size_t)t * NH + c) = o;
}

extern "C" void kernel_launch(void* const* d_in, const int* in_sizes, int n_in,
                              void* d_out, int out_size, void* d_ws, size_t ws_size,
                              hipStream_t stream) {
    const float* x      = (const float*)d_in[0];
    const float* logits = (const float*)d_in[1];
    const int*   w13q   = (const int*)d_in[2];
    const int*   w2q    = (const int*)d_in[3];
    const float* s13    = (const float*)d_in[4];
    const float* s2     = (const float*)d_in[5];

    char* ws = (char*)d_ws;
    size_t o = 0;
    int*   counts   = (int*)(ws + o);   o += 4096;
    int*   offs     = (int*)(ws + o);   o += 4096;
    float* topk_w   = (float*)(ws + o); o += 4096;
    int*   tok_list = (int*)(ws + o);   o += 16384;
    int*   rowmap   = (int*)(ws + o);   o += 4096;
    int*   inv      = (int*)(ws + o);   o += 4096;
    float* sx       = (float*)(ws + o); o += 4096;
    char*  xq       = ws + o;           o += (size_t)2 * NT * NH;          // 1 MB
    short* a_s      = (short*)(ws + o); o += (size_t)2 * NT * NF * 2;      // 5.77 MB
    float* y_s      = (float*)(ws + o); o += (size_t)2 * NT * NH * 4;      // 4 MB

    route_bin_kernel<<<1, 512, 0, stream>>>(logits, topk_w, counts, offs,
                                            tok_list, rowmap, inv);
    quant_x_kernel<<<2 * NT, 256, 0, stream>>>(x, rowmap, xq, sx);
    gemm1_act_kernel<<<dim3(NF / 32, 8, NE), 256, 0, stream>>>(
        xq, sx, w13q, s13, counts, offs, a_s);
    gemm2_kernel<<<dim3(NH / 32, 32, NE), 256, 0, stream>>>(
        a_s, w2q, s2, counts, offs, y_s);
    combine_kernel<<<NT, 256, 0, stream>>>(y_s, inv, topk_w, (float*)d_out);
}